// Round 20
// baseline (114.044 us; speedup 1.0000x reference)
//
#include <hip/hip_runtime.h>

// Chamfer loss via MFMA, B=8, N=M=8192, D=3, fp32.
// D[i][j] = ||p_i||^2 + ||s_j||^2 - 2 p_i.s_j via mfma_f32_32x32x16_bf16,
// bf16 hi/lo split (exact to ~2^-18 rel). k-slot layout as R7 (verified).
// R19 = R15 (best total 48.65us) with hot loop unrolled 4->8 tiles/iter:
// 8 independent ds_read_b128 in flight per iteration to cover the ~120cyc
// LDS latency (kernel is latency-bound: per-SIMD MFMA 7.6%, VALU 12%).
// NO fences/asm in the loop (R8/R11/R17 spill-or-corrupt lesson).

typedef __attribute__((ext_vector_type(8))) short short8;
typedef __attribute__((ext_vector_type(16))) float f32x16;
typedef unsigned int uint32;

#define NPTS 8192
#define BATCH 8
#define PER_DIR (BATCH * NPTS)  // 65536 rows per direction
#define SSPLIT 4
#define SLICE (NPTS / SSPLIT)   // 2048 scan rows per block

__device__ __forceinline__ unsigned short f2bf(float f) {
  uint32 u = __float_as_uint(f);
  return (unsigned short)((u + 0x7FFFu + ((u >> 16) & 1u)) >> 16);  // RNE
}
__device__ __forceinline__ float bf2f(unsigned short h) {
  return __uint_as_float(((uint32)h) << 16);
}
__device__ __forceinline__ uint32 umin2(uint32 a, uint32 b) {
  return __builtin_elementwise_min(a, b);
}

// 1024 blocks: dir(2) x batch(8) x oc(16) x sp(SSPLIT=4).
// 512 thr = 8 waves; block stages its 2048-row scan slice into 64 KB LDS
// (fragment layout), then each wave scans 64 tiles, 8 tiles/iter,
// vs its 64 owned rows.
__global__ __launch_bounds__(512, 4) void chamfer_mfma_kernel(
    const float* __restrict__ preds, const float* __restrict__ gts,
    float* __restrict__ partMins) {
  __shared__ uint4 sTile[SLICE * 2];  // 64 KB: chunk L = t*64 + lanepos
  const int tid = threadIdx.x;
  const int lane = tid & 63;
  const int wid = tid >> 6;      // 0..7
  const int half = lane >> 5;    // k-group: 0 -> k0-7, 1 -> k8-15
  const int lr = lane & 31;      // row (A) / col (B) slot

  int id = blockIdx.x;
  const int blocksPerDir = BATCH * 16 * SSPLIT;  // 512
  const int dir = id / blocksPerDir;
  id %= blocksPerDir;
  const int b = id / (16 * SSPLIT);
  const int rem = id % (16 * SSPLIT);
  const int oc = rem / SSPLIT;
  const int sp = rem % SSPLIT;

  const float* own =
      (dir == 0 ? preds : gts) + ((size_t)b * NPTS + oc * 512) * 3;
  const float* scanRaw =
      (dir == 0 ? gts : preds) + ((size_t)b * NPTS + sp * SLICE) * 3;

  // ---- Stage: transform raw slice points -> fragment chunks in LDS.
#pragma unroll
  for (int k = 0; k < SLICE / 512; ++k) {
    int j = tid + k * 512;
    float x = scanRaw[3 * j], y = scanRaw[3 * j + 1], z = scanRaw[3 * j + 2];
    float ws = fmaf(x, x, fmaf(y, y, z * z));
    unsigned short bhx = f2bf(x), bhy = f2bf(y), bhz = f2bf(z);
    unsigned short blx = f2bf(x - bf2f(bhx));
    unsigned short bly = f2bf(y - bf2f(bhy));
    unsigned short blz = f2bf(z - bf2f(bhz));
    unsigned short wsh = f2bf(ws);
    unsigned short wsl = f2bf(ws - bf2f(wsh));
    const unsigned short one = 0x3F80;
    uint4 w0, w1;
    w0.x = (uint32)bhx | ((uint32)bhy << 16);
    w0.y = (uint32)bhz | ((uint32)blx << 16);
    w0.z = (uint32)bly | ((uint32)blz << 16);
    w0.w = (uint32)bhx | ((uint32)bhy << 16);
    w1.x = (uint32)bhz | ((uint32)blx << 16);
    w1.y = (uint32)bly | ((uint32)blz << 16);
    w1.z = (uint32)wsh | ((uint32)wsl << 16);
    w1.w = (uint32)one | ((uint32)one << 16);
    int t = j >> 5, c = j & 31;
    sTile[t * 64 + c] = w0;
    sTile[t * 64 + 32 + c] = w1;
  }

  // ---- Build the two A fragments (rows wid*64+lr and wid*64+32+lr).
  short8 A[2];
#pragma unroll
  for (int f = 0; f < 2; ++f) {
    int row = wid * 64 + f * 32 + lr;
    float x = own[3 * row], y = own[3 * row + 1], z = own[3 * row + 2];
    float ax = -2.0f * x, ay = -2.0f * y, az = -2.0f * z;
    unsigned short ahx = f2bf(ax), ahy = f2bf(ay), ahz = f2bf(az);
    unsigned short alx = f2bf(ax - bf2f(ahx));
    unsigned short aly = f2bf(ay - bf2f(ahy));
    unsigned short alz = f2bf(az - bf2f(ahz));
    float wp = fmaf(x, x, fmaf(y, y, z * z));
    unsigned short wph = f2bf(wp);
    unsigned short wpl = f2bf(wp - bf2f(wph));
    const unsigned short one = 0x3F80;
    unsigned short e0, e1, e2, e3, e4, e5, e6, e7;
    if (half == 0) {
      e0 = ahx; e1 = ahy; e2 = ahz; e3 = ahx;
      e4 = ahy; e5 = ahz; e6 = alx; e7 = aly;
    } else {
      e0 = alz; e1 = alx; e2 = aly; e3 = alz;
      e4 = one; e5 = one; e6 = wph; e7 = wpl;
    }
    short8 a;
    a[0] = (short)e0; a[1] = (short)e1; a[2] = (short)e2; a[3] = (short)e3;
    a[4] = (short)e4; a[5] = (short)e5; a[6] = (short)e6; a[7] = (short)e7;
    A[f] = a;
  }

  f32x16 zc;
  uint32 m0[16], m1[16];
#pragma unroll
  for (int r = 0; r < 16; ++r) {
    zc[r] = 0.0f;
    m0[r] = __float_as_uint(3.0e38f);
    m1[r] = __float_as_uint(3.0e38f);
  }

  __syncthreads();

  const short8* Bv = (const short8*)sTile;
  constexpr int scanTiles = SLICE / 32;  // 64

  for (int t = 0; t < scanTiles; t += 8) {
    short8 b0 = Bv[(t + 0) * 64 + lane];
    short8 b1 = Bv[(t + 1) * 64 + lane];
    short8 b2 = Bv[(t + 2) * 64 + lane];
    short8 b3 = Bv[(t + 3) * 64 + lane];
    short8 b4 = Bv[(t + 4) * 64 + lane];
    short8 b5 = Bv[(t + 5) * 64 + lane];
    short8 b6 = Bv[(t + 6) * 64 + lane];
    short8 b7 = Bv[(t + 7) * 64 + lane];
    f32x16 D00 = __builtin_amdgcn_mfma_f32_32x32x16_bf16(A[0], b0, zc, 0, 0, 0);
    f32x16 D10 = __builtin_amdgcn_mfma_f32_32x32x16_bf16(A[1], b0, zc, 0, 0, 0);
    f32x16 D01 = __builtin_amdgcn_mfma_f32_32x32x16_bf16(A[0], b1, zc, 0, 0, 0);
    f32x16 D11 = __builtin_amdgcn_mfma_f32_32x32x16_bf16(A[1], b1, zc, 0, 0, 0);
#pragma unroll
    for (int r = 0; r < 16; ++r) {
      m0[r] = umin2(umin2(m0[r], __float_as_uint(D00[r])),
                    __float_as_uint(D01[r]));
      m1[r] = umin2(umin2(m1[r], __float_as_uint(D10[r])),
                    __float_as_uint(D11[r]));
    }
    f32x16 D02 = __builtin_amdgcn_mfma_f32_32x32x16_bf16(A[0], b2, zc, 0, 0, 0);
    f32x16 D12 = __builtin_amdgcn_mfma_f32_32x32x16_bf16(A[1], b2, zc, 0, 0, 0);
    f32x16 D03 = __builtin_amdgcn_mfma_f32_32x32x16_bf16(A[0], b3, zc, 0, 0, 0);
    f32x16 D13 = __builtin_amdgcn_mfma_f32_32x32x16_bf16(A[1], b3, zc, 0, 0, 0);
#pragma unroll
    for (int r = 0; r < 16; ++r) {
      m0[r] = umin2(umin2(m0[r], __float_as_uint(D02[r])),
                    __float_as_uint(D03[r]));
      m1[r] = umin2(umin2(m1[r], __float_as_uint(D12[r])),
                    __float_as_uint(D13[r]));
    }
    f32x16 D04 = __builtin_amdgcn_mfma_f32_32x32x16_bf16(A[0], b4, zc, 0, 0, 0);
    f32x16 D14 = __builtin_amdgcn_mfma_f32_32x32x16_bf16(A[1], b4, zc, 0, 0, 0);
    f32x16 D05 = __builtin_amdgcn_mfma_f32_32x32x16_bf16(A[0], b5, zc, 0, 0, 0);
    f32x16 D15 = __builtin_amdgcn_mfma_f32_32x32x16_bf16(A[1], b5, zc, 0, 0, 0);
#pragma unroll
    for (int r = 0; r < 16; ++r) {
      m0[r] = umin2(umin2(m0[r], __float_as_uint(D04[r])),
                    __float_as_uint(D05[r]));
      m1[r] = umin2(umin2(m1[r], __float_as_uint(D14[r])),
                    __float_as_uint(D15[r]));
    }
    f32x16 D06 = __builtin_amdgcn_mfma_f32_32x32x16_bf16(A[0], b6, zc, 0, 0, 0);
    f32x16 D16 = __builtin_amdgcn_mfma_f32_32x32x16_bf16(A[1], b6, zc, 0, 0, 0);
    f32x16 D07 = __builtin_amdgcn_mfma_f32_32x32x16_bf16(A[0], b7, zc, 0, 0, 0);
    f32x16 D17 = __builtin_amdgcn_mfma_f32_32x32x16_bf16(A[1], b7, zc, 0, 0, 0);
#pragma unroll
    for (int r = 0; r < 16; ++r) {
      m0[r] = umin2(umin2(m0[r], __float_as_uint(D06[r])),
                    __float_as_uint(D07[r]));
      m1[r] = umin2(umin2(m1[r], __float_as_uint(D16[r])),
                    __float_as_uint(D17[r]));
    }
  }

  // Min over the 32 col-slots (butterfly within each 32-lane group).
#pragma unroll
  for (int off = 1; off < 32; off <<= 1) {
#pragma unroll
    for (int r = 0; r < 16; ++r) {
      m0[r] = umin2(m0[r], (uint32)__shfl_xor((int)m0[r], off, 64));
      m1[r] = umin2(m1[r], (uint32)__shfl_xor((int)m1[r], off, 64));
    }
  }

  // Store per-row partial mins (rows distinct & bijective over (r,half)).
  float* outp = partMins + ((size_t)dir * SSPLIT + sp) * PER_DIR +
                (size_t)b * NPTS + oc * 512 + wid * 64;
  if (lr == 0) {
#pragma unroll
    for (int r = 0; r < 16; ++r) {
      int rowid = (r & 3) + 8 * (r >> 2) + 4 * half;
      outp[rowid] = __uint_as_float(m0[r]);
      outp[32 + rowid] = __uint_as_float(m1[r]);
    }
  }
}

// Min over SSPLIT partials per row, sum per block. partMins: [2][SSPLIT][PER_DIR].
__global__ __launch_bounds__(256) void reduce_a_kernel(
    const float* __restrict__ partMins, float* __restrict__ blockSums) {
  const int nSlots = 2 * PER_DIR;  // 131072
  const int gid = blockIdx.x * 256 + threadIdx.x;
  const int stride = 128 * 256;
  float s = 0.0f;
  for (int sl = gid; sl < nSlots; sl += stride) {
    const int dir = sl >> 16;          // PER_DIR == 65536
    const int idx = sl & (PER_DIR - 1);
    const float* base = partMins + (size_t)dir * SSPLIT * PER_DIR + idx;
    float mn = base[0];
#pragma unroll
    for (int sp = 1; sp < SSPLIT; ++sp)
      mn = fminf(mn, base[(size_t)sp * PER_DIR]);
    s += mn;
  }
#pragma unroll
  for (int off = 32; off > 0; off >>= 1) s += __shfl_down(s, off, 64);
  __shared__ float part[4];
  int wid = threadIdx.x >> 6, lane = threadIdx.x & 63;
  if (lane == 0) part[wid] = s;
  __syncthreads();
  if (threadIdx.x == 0)
    blockSums[blockIdx.x] = part[0] + part[1] + part[2] + part[3];
}

__global__ __launch_bounds__(128) void reduce_b_kernel(
    const float* __restrict__ blockSums, float* __restrict__ out) {
  float s = blockSums[threadIdx.x];
#pragma unroll
  for (int off = 32; off > 0; off >>= 1) s += __shfl_down(s, off, 64);
  __shared__ float part[2];
  int wid = threadIdx.x >> 6, lane = threadIdx.x & 63;
  if (lane == 0) part[wid] = s;
  __syncthreads();
  if (threadIdx.x == 0) out[0] = part[0] + part[1];
}

extern "C" void kernel_launch(void* const* d_in, const int* in_sizes, int n_in,
                              void* d_out, int out_size, void* d_ws,
                              size_t ws_size, hipStream_t stream) {
  const float* preds = (const float*)d_in[0];  // [B, M, 3]
  const float* gts = (const float*)d_in[1];    // [B, N, 3]

  // ws: partMins [2][SSPLIT][PER_DIR] f32 (2MB) | blockSums[128]
  float* partMins = (float*)d_ws;
  float* blockSums = partMins + (size_t)2 * SSPLIT * PER_DIR;

  chamfer_mfma_kernel<<<2 * BATCH * 16 * SSPLIT, 512, 0, stream>>>(
      preds, gts, partMins);
  reduce_a_kernel<<<128, 256, 0, stream>>>(partMins, blockSums);
  reduce_b_kernel<<<1, 128, 0, stream>>>(blockSums, (float*)d_out);
}

// Round 21
// 48.247 us; speedup vs baseline: 2.3638x; 2.3638x over previous
//
#include <hip/hip_runtime.h>

// Chamfer loss via MFMA, B=8, N=M=8192, D=3, fp32.
// D[i][j] = ||p_i||^2 + ||s_j||^2 - 2 p_i.s_j via mfma_f32_32x32x16_bf16,
// bf16 hi/lo split (exact to ~2^-18 rel). k-slot layout as R7 (verified).
// R20 = R15 hot loop, block rescaled 512->1024 threads (16 waves/block).
// Rationale: R13->R14 showed halving LDS does NOT raise occupancy => the
// residency limiter is co-resident BLOCKS per CU (~2), not LDS/VGPR. More
// waves per block doubles resident waves at the same block count.
// NO fences/asm in loop; unroll stays 4 (R19: unroll-8 spilled 435MB).

typedef __attribute__((ext_vector_type(8))) short short8;
typedef __attribute__((ext_vector_type(16))) float f32x16;
typedef unsigned int uint32;

#define NPTS 8192
#define BATCH 8
#define PER_DIR (BATCH * NPTS)  // 65536 rows per direction
#define SSPLIT 4
#define SLICE (NPTS / SSPLIT)   // 2048 scan rows per block
#define OWNPB 1024              // own rows per block (16 waves x 64)

__device__ __forceinline__ unsigned short f2bf(float f) {
  uint32 u = __float_as_uint(f);
  return (unsigned short)((u + 0x7FFFu + ((u >> 16) & 1u)) >> 16);  // RNE
}
__device__ __forceinline__ float bf2f(unsigned short h) {
  return __uint_as_float(((uint32)h) << 16);
}
__device__ __forceinline__ uint32 umin2(uint32 a, uint32 b) {
  return __builtin_elementwise_min(a, b);
}

// 512 blocks: dir(2) x batch(8) x oc(8) x sp(SSPLIT=4). 1024 thr = 16 waves.
// Block stages its 2048-row scan slice into 64 KB LDS (fragment layout);
// each wave scans 64 tiles, 4 tiles/iter, vs its 64 owned rows.
__global__ __launch_bounds__(1024, 4) void chamfer_mfma_kernel(
    const float* __restrict__ preds, const float* __restrict__ gts,
    float* __restrict__ partMins) {
  __shared__ uint4 sTile[SLICE * 2];  // 64 KB: chunk L = t*64 + lanepos
  const int tid = threadIdx.x;
  const int lane = tid & 63;
  const int wid = tid >> 6;      // 0..15
  const int half = lane >> 5;    // k-group: 0 -> k0-7, 1 -> k8-15
  const int lr = lane & 31;      // row (A) / col (B) slot

  int id = blockIdx.x;
  const int ocN = NPTS / OWNPB;                  // 8
  const int blocksPerDir = BATCH * ocN * SSPLIT; // 256
  const int dir = id / blocksPerDir;
  id %= blocksPerDir;
  const int b = id / (ocN * SSPLIT);
  const int rem = id % (ocN * SSPLIT);
  const int oc = rem / SSPLIT;
  const int sp = rem % SSPLIT;

  const float* own =
      (dir == 0 ? preds : gts) + ((size_t)b * NPTS + oc * OWNPB) * 3;
  const float* scanRaw =
      (dir == 0 ? gts : preds) + ((size_t)b * NPTS + sp * SLICE) * 3;

  // ---- Stage: transform raw slice points -> fragment chunks in LDS.
#pragma unroll
  for (int k = 0; k < SLICE / 1024; ++k) {
    int j = tid + k * 1024;
    float x = scanRaw[3 * j], y = scanRaw[3 * j + 1], z = scanRaw[3 * j + 2];
    float ws = fmaf(x, x, fmaf(y, y, z * z));
    unsigned short bhx = f2bf(x), bhy = f2bf(y), bhz = f2bf(z);
    unsigned short blx = f2bf(x - bf2f(bhx));
    unsigned short bly = f2bf(y - bf2f(bhy));
    unsigned short blz = f2bf(z - bf2f(bhz));
    unsigned short wsh = f2bf(ws);
    unsigned short wsl = f2bf(ws - bf2f(wsh));
    const unsigned short one = 0x3F80;
    uint4 w0, w1;
    w0.x = (uint32)bhx | ((uint32)bhy << 16);
    w0.y = (uint32)bhz | ((uint32)blx << 16);
    w0.z = (uint32)bly | ((uint32)blz << 16);
    w0.w = (uint32)bhx | ((uint32)bhy << 16);
    w1.x = (uint32)bhz | ((uint32)blx << 16);
    w1.y = (uint32)bly | ((uint32)blz << 16);
    w1.z = (uint32)wsh | ((uint32)wsl << 16);
    w1.w = (uint32)one | ((uint32)one << 16);
    int t = j >> 5, c = j & 31;
    sTile[t * 64 + c] = w0;
    sTile[t * 64 + 32 + c] = w1;
  }

  // ---- Build the two A fragments (rows wid*64+lr and wid*64+32+lr).
  short8 A[2];
#pragma unroll
  for (int f = 0; f < 2; ++f) {
    int row = wid * 64 + f * 32 + lr;
    float x = own[3 * row], y = own[3 * row + 1], z = own[3 * row + 2];
    float ax = -2.0f * x, ay = -2.0f * y, az = -2.0f * z;
    unsigned short ahx = f2bf(ax), ahy = f2bf(ay), ahz = f2bf(az);
    unsigned short alx = f2bf(ax - bf2f(ahx));
    unsigned short aly = f2bf(ay - bf2f(ahy));
    unsigned short alz = f2bf(az - bf2f(ahz));
    float wp = fmaf(x, x, fmaf(y, y, z * z));
    unsigned short wph = f2bf(wp);
    unsigned short wpl = f2bf(wp - bf2f(wph));
    const unsigned short one = 0x3F80;
    unsigned short e0, e1, e2, e3, e4, e5, e6, e7;
    if (half == 0) {
      e0 = ahx; e1 = ahy; e2 = ahz; e3 = ahx;
      e4 = ahy; e5 = ahz; e6 = alx; e7 = aly;
    } else {
      e0 = alz; e1 = alx; e2 = aly; e3 = alz;
      e4 = one; e5 = one; e6 = wph; e7 = wpl;
    }
    short8 a;
    a[0] = (short)e0; a[1] = (short)e1; a[2] = (short)e2; a[3] = (short)e3;
    a[4] = (short)e4; a[5] = (short)e5; a[6] = (short)e6; a[7] = (short)e7;
    A[f] = a;
  }

  f32x16 zc;
  uint32 m0[16], m1[16];
#pragma unroll
  for (int r = 0; r < 16; ++r) {
    zc[r] = 0.0f;
    m0[r] = __float_as_uint(3.0e38f);
    m1[r] = __float_as_uint(3.0e38f);
  }

  __syncthreads();

  const short8* Bv = (const short8*)sTile;
  constexpr int scanTiles = SLICE / 32;  // 64

  for (int t = 0; t < scanTiles; t += 4) {
    short8 b0 = Bv[(t + 0) * 64 + lane];
    short8 b1 = Bv[(t + 1) * 64 + lane];
    short8 b2 = Bv[(t + 2) * 64 + lane];
    short8 b3 = Bv[(t + 3) * 64 + lane];
    f32x16 D00 = __builtin_amdgcn_mfma_f32_32x32x16_bf16(A[0], b0, zc, 0, 0, 0);
    f32x16 D10 = __builtin_amdgcn_mfma_f32_32x32x16_bf16(A[1], b0, zc, 0, 0, 0);
    f32x16 D01 = __builtin_amdgcn_mfma_f32_32x32x16_bf16(A[0], b1, zc, 0, 0, 0);
    f32x16 D11 = __builtin_amdgcn_mfma_f32_32x32x16_bf16(A[1], b1, zc, 0, 0, 0);
    f32x16 D02 = __builtin_amdgcn_mfma_f32_32x32x16_bf16(A[0], b2, zc, 0, 0, 0);
    f32x16 D12 = __builtin_amdgcn_mfma_f32_32x32x16_bf16(A[1], b2, zc, 0, 0, 0);
    f32x16 D03 = __builtin_amdgcn_mfma_f32_32x32x16_bf16(A[0], b3, zc, 0, 0, 0);
    f32x16 D13 = __builtin_amdgcn_mfma_f32_32x32x16_bf16(A[1], b3, zc, 0, 0, 0);
#pragma unroll
    for (int r = 0; r < 16; ++r) {
      m0[r] = umin2(umin2(m0[r], __float_as_uint(D00[r])),
                    __float_as_uint(D01[r]));
      m0[r] = umin2(umin2(m0[r], __float_as_uint(D02[r])),
                    __float_as_uint(D03[r]));
      m1[r] = umin2(umin2(m1[r], __float_as_uint(D10[r])),
                    __float_as_uint(D11[r]));
      m1[r] = umin2(umin2(m1[r], __float_as_uint(D12[r])),
                    __float_as_uint(D13[r]));
    }
  }

  // Min over the 32 col-slots (butterfly within each 32-lane group).
#pragma unroll
  for (int off = 1; off < 32; off <<= 1) {
#pragma unroll
    for (int r = 0; r < 16; ++r) {
      m0[r] = umin2(m0[r], (uint32)__shfl_xor((int)m0[r], off, 64));
      m1[r] = umin2(m1[r], (uint32)__shfl_xor((int)m1[r], off, 64));
    }
  }

  // Store per-row partial mins (rows distinct & bijective over (r,half)).
  float* outp = partMins + ((size_t)dir * SSPLIT + sp) * PER_DIR +
                (size_t)b * NPTS + oc * OWNPB + wid * 64;
  if (lr == 0) {
#pragma unroll
    for (int r = 0; r < 16; ++r) {
      int rowid = (r & 3) + 8 * (r >> 2) + 4 * half;
      outp[rowid] = __uint_as_float(m0[r]);
      outp[32 + rowid] = __uint_as_float(m1[r]);
    }
  }
}

// Min over SSPLIT partials per row, sum per block. partMins: [2][SSPLIT][PER_DIR].
__global__ __launch_bounds__(256) void reduce_a_kernel(
    const float* __restrict__ partMins, float* __restrict__ blockSums) {
  const int nSlots = 2 * PER_DIR;  // 131072
  const int gid = blockIdx.x * 256 + threadIdx.x;
  const int stride = 128 * 256;
  float s = 0.0f;
  for (int sl = gid; sl < nSlots; sl += stride) {
    const int dir = sl >> 16;          // PER_DIR == 65536
    const int idx = sl & (PER_DIR - 1);
    const float* base = partMins + (size_t)dir * SSPLIT * PER_DIR + idx;
    float mn = base[0];
#pragma unroll
    for (int sp = 1; sp < SSPLIT; ++sp)
      mn = fminf(mn, base[(size_t)sp * PER_DIR]);
    s += mn;
  }
#pragma unroll
  for (int off = 32; off > 0; off >>= 1) s += __shfl_down(s, off, 64);
  __shared__ float part[4];
  int wid = threadIdx.x >> 6, lane = threadIdx.x & 63;
  if (lane == 0) part[wid] = s;
  __syncthreads();
  if (threadIdx.x == 0)
    blockSums[blockIdx.x] = part[0] + part[1] + part[2] + part[3];
}

__global__ __launch_bounds__(128) void reduce_b_kernel(
    const float* __restrict__ blockSums, float* __restrict__ out) {
  float s = blockSums[threadIdx.x];
#pragma unroll
  for (int off = 32; off > 0; off >>= 1) s += __shfl_down(s, off, 64);
  __shared__ float part[2];
  int wid = threadIdx.x >> 6, lane = threadIdx.x & 63;
  if (lane == 0) part[wid] = s;
  __syncthreads();
  if (threadIdx.x == 0) out[0] = part[0] + part[1];
}

extern "C" void kernel_launch(void* const* d_in, const int* in_sizes, int n_in,
                              void* d_out, int out_size, void* d_ws,
                              size_t ws_size, hipStream_t stream) {
  const float* preds = (const float*)d_in[0];  // [B, M, 3]
  const float* gts = (const float*)d_in[1];    // [B, N, 3]

  // ws: partMins [2][SSPLIT][PER_DIR] f32 (2MB) | blockSums[128]
  float* partMins = (float*)d_ws;
  float* blockSums = partMins + (size_t)2 * SSPLIT * PER_DIR;

  chamfer_mfma_kernel<<<2 * BATCH * (NPTS / OWNPB) * SSPLIT, 1024, 0, stream>>>(
      preds, gts, partMins);
  reduce_a_kernel<<<128, 256, 0, stream>>>(partMins, blockSums);
  reduce_b_kernel<<<1, 128, 0, stream>>>(blockSums, (float*)d_out);
}